// Round 1
// 409.563 us; speedup vs baseline: 1.0159x; 1.0159x over previous
//
#include <hip/hip_runtime.h>
#include <stdint.h>

#define B_N 4096
#define T_N 17
#define C_N 512
#define KTOT 1024   // K = [x | trend] = 2*C_N

typedef __bf16 bf16x8 __attribute__((ext_vector_type(8)));
typedef float  f32x4  __attribute__((ext_vector_type(4)));

// fp32 -> bf16 round-to-nearest-even (finite inputs)
__device__ __forceinline__ unsigned short f2b(float f){
  unsigned u = __float_as_uint(f);
  return (unsigned short)((u + 0x7fffu + ((u >> 16) & 1u)) >> 16);
}
__device__ __forceinline__ unsigned pk2(float a, float b){
  return (unsigned)f2b(a) | ((unsigned)f2b(b) << 16);
}

// async global->LDS, 16B/lane. LDS dest is wave-uniform base + lane*16; our
// per-lane dest addresses are exactly that (chunk ids are lane-consecutive).
__device__ __forceinline__ void gll16(const void* g, void* l){
  __builtin_amdgcn_global_load_lds(
      (const __attribute__((address_space(1))) unsigned int*)g,
      (__attribute__((address_space(3))) unsigned int*)l, 16, 0, 0);
}

#define BAR()   __builtin_amdgcn_s_barrier()
#define LGKM0() do{ asm volatile("s_waitcnt lgkmcnt(0)" ::: "memory"); \
                    __builtin_amdgcn_sched_barrier(0); }while(0)
#define VMC(n)  do{ asm volatile("s_waitcnt vmcnt(" #n ")" ::: "memory"); \
                    __builtin_amdgcn_sched_barrier(0); }while(0)

// ---------------------------------------------------------------------------
// prep_w: Wcat[t][d][0:512] = bf16(Ws), [512:1024] = bf16(Wt - Ws)
// 17*512*512/8 = 557056 threads
// ---------------------------------------------------------------------------
__global__ __launch_bounds__(256) void prep_w(
    const float* __restrict__ Ws, const float* __restrict__ Wt,
    unsigned short* __restrict__ wcat)
{
  const size_t i8 = ((size_t)blockIdx.x * 256 + threadIdx.x) * 8;
  const int t   = (int)(i8 >> 18);          // / (512*512)
  const int rem = (int)(i8 & 262143);
  const int d   = rem >> 9;
  const int c   = rem & 511;
  float4 a0 = *(const float4*)(Ws + i8);
  float4 a1 = *(const float4*)(Ws + i8 + 4);
  float4 b0 = *(const float4*)(Wt + i8);
  float4 b1 = *(const float4*)(Wt + i8 + 4);
  uint4 oa, od;
  oa.x = pk2(a0.x, a0.y); oa.y = pk2(a0.z, a0.w);
  oa.z = pk2(a1.x, a1.y); oa.w = pk2(a1.z, a1.w);
  od.x = pk2(b0.x - a0.x, b0.y - a0.y); od.y = pk2(b0.z - a0.z, b0.w - a0.w);
  od.z = pk2(b1.x - a1.x, b1.y - a1.y); od.w = pk2(b1.z - a1.z, b1.w - a1.w);
  unsigned short* base = wcat + ((size_t)(t * C_N + d)) * KTOT + c;
  *(uint4*)base = oa;
  *(uint4*)(base + C_N) = od;
}

__global__ __launch_bounds__(256) void prep_bsum(
    const float* __restrict__ bs, const float* __restrict__ bt, float* __restrict__ o)
{
  const int i = blockIdx.x * 256 + threadIdx.x;
  o[i] = bs[i] + bt[i];
}

// ---------------------------------------------------------------------------
// prep_a: one pass over x. Acat[t][b][0:512] = bf16(x[b,t,:]),
//         Acat[t][b][512:1024] = bf16(trend[b,t,:]) with trend = u + t*v,
//         u = (S + 18*x0 + 2*x16)/37, v = (x16 - x0)/37.
// ---------------------------------------------------------------------------
__global__ __launch_bounds__(256) void prep_a(
    const float* __restrict__ x, unsigned short* __restrict__ acat)
{
  const int idx = blockIdx.x * 256 + threadIdx.x;   // 4096 * 64 = 262144
  const int b = idx >> 6;
  const int c = (idx & 63) << 3;
  const float* xp = x + (size_t)b * (T_N * C_N) + c;
  float s[8] = {0,0,0,0,0,0,0,0};
  float f0[8], fl[8];
#pragma unroll
  for (int tt = 0; tt < T_N; ++tt){
    float4 w0 = *(const float4*)(xp + (size_t)tt * C_N);
    float4 w1 = *(const float4*)(xp + (size_t)tt * C_N + 4);
    float f[8] = {w0.x, w0.y, w0.z, w0.w, w1.x, w1.y, w1.z, w1.w};
    uint4 o;
    o.x = pk2(f[0],f[1]); o.y = pk2(f[2],f[3]);
    o.z = pk2(f[4],f[5]); o.w = pk2(f[6],f[7]);
    *(uint4*)(acat + ((size_t)tt * B_N + b) * KTOT + c) = o;
    if (tt == 0){
#pragma unroll
      for (int i=0;i<8;++i) f0[i] = f[i];
    }
    if (tt == T_N-1){
#pragma unroll
      for (int i=0;i<8;++i) fl[i] = f[i];
    }
#pragma unroll
    for (int i=0;i<8;++i) s[i] += f[i];
  }
  const float inv = 1.0f / 37.0f;
  float uu[8], vv[8];
#pragma unroll
  for (int i=0;i<8;++i){
    uu[i] = (s[i] + 18.0f * f0[i] + 2.0f * fl[i]) * inv;
    vv[i] = (fl[i] - f0[i]) * inv;
  }
#pragma unroll
  for (int tt = 0; tt < T_N; ++tt){
    const float tfv = (float)tt;
    float tr[8];
#pragma unroll
    for (int i=0;i<8;++i) tr[i] = fmaf(tfv, vv[i], uu[i]);
    uint4 o;
    o.x = pk2(tr[0],tr[1]); o.y = pk2(tr[2],tr[3]);
    o.z = pk2(tr[4],tr[5]); o.w = pk2(tr[6],tr[7]);
    *(uint4*)(acat + ((size_t)tt * B_N + b) * KTOT + C_N + c) = o;
  }
}

// ---------------------------------------------------------------------------
// gemm8: per token t, out[:,t,:] = Acat[t] (4096x1024) * Wcat[t]^T (512x1024)
//        + bsum[t], fp32 store.
// 256x256 tile, BK=64, 8 waves (2M x 4N), mfma_f32_16x16x32_bf16,
// 8-phase schedule: 4 phases/K-tile x 16 MFMA, counted vmcnt(8), raw
// s_barrier + lgkmcnt(0), setprio around MFMA, XOR-swizzled LDS (chunk
// cc of row r holds global chunk cc ^ (r&7); inverse-swizzled global src
// keeps the LDS dest linear for global_load_lds).
// Staging discipline (per 4-phase group computing K-tile kc from buf bb,
// staging kc+2 into bb): B tile staged at ph2 (B last read ph1),
// A tile staged at ph3 (A last read ph2). vmcnt(8) at ph3 forces the
// previous K-tile's 8 loads landed; this group's 8 fly 4-5 more phases.
// ---------------------------------------------------------------------------
__global__ __launch_bounds__(512) void gemm8(
    const unsigned short* __restrict__ acat,
    const unsigned short* __restrict__ wcat,
    const float* __restrict__ bsum,
    float* __restrict__ out)
{
  __shared__ alignas(16) unsigned short A_lds[2][256][64];
  __shared__ alignas(16) unsigned short B_lds[2][256][64];

  const int tid = threadIdx.x;
  const int bid = blockIdx.x;
  // XCD-contiguous swizzle: 544 blocks = 8 XCDs * 68 (exact -> bijective)
  const int wg = (bid & 7) * 68 + (bid >> 3);
  const int t  = wg >> 5;            // 17 tokens * 32 tiles
  const int mt = (wg >> 1) & 15;     // 16 M-tiles of 256
  const int nt = wg & 1;             // 2 N-tiles of 256
  const int m0 = mt << 8;
  const int n0 = nt << 8;

  const int lane = tid & 63;
  const int wave = tid >> 6;
  const int wr = wave >> 2;          // 0..1 : wave row  (128 M rows each)
  const int wc = wave & 3;           // 0..3 : wave col  (64 N cols each)
  const int lr = lane & 15;
  const int g  = lane >> 4;          // k-chunk group 0..3

  // ---- staging bases: chunk c = r*512 + tid; row = c>>3; cc = c&7.
  // row&7 and cc are r-invariant, so one base + constant strides suffice.
  const int row0 = tid >> 3;               // 0..63
  const int cc0  = tid & 7;
  const int cswz = ((cc0 ^ (row0 & 7)) << 3);   // inverse-swizzled src col (ush)
  const unsigned short* gA0 = acat + ((size_t)t * B_N + m0 + row0) * KTOT + cswz;
  const unsigned short* gB0 = wcat + ((size_t)t * C_N + n0 + row0) * KTOT + cswz;
  unsigned short* lA0 = &A_lds[0][row0][cc0 << 3];
  unsigned short* lB0 = &B_lds[0][row0][cc0 << 3];

  auto stageA = [&](int bb, int kt){
#pragma unroll
    for (int r = 0; r < 4; ++r)            // rows r*64+row0, dest = tid*16B linear
      gll16(gA0 + (size_t)kt * 64 + r * 65536, lA0 + bb * 16384 + r * 4096);
  };
  auto stageB = [&](int bb, int kt){
#pragma unroll
    for (int r = 0; r < 4; ++r)
      gll16(gB0 + (size_t)kt * 64 + r * 65536, lB0 + bb * 16384 + r * 4096);
  };

  // ---- fragment-read bases (swizzled): row = {wr*128|wc*64} + fragrow*16 + lr,
  // chunk for k-step ks, group g is (ks*4+g) ^ (row&7); row&7 == lr&7.
  const int sw  = lr & 7;
  const int ca0 = (( g     ) ^ sw) << 3;   // ks0 chunk offset (ush)
  const int ca1 = ((4 | g  ) ^ sw) << 3;   // ks1 chunk offset (ush)
  const unsigned short* Arow = &A_lds[0][wr * 128 + lr][0];
  const unsigned short* Brow = &B_lds[0][wc * 64  + lr][0];

  f32x4 acc[8][4];
#pragma unroll
  for (int i=0;i<8;++i)
#pragma unroll
    for (int j=0;j<4;++j){ f32x4 z = {0.f,0.f,0.f,0.f}; acc[i][j] = z; }

  auto rdA4 = [&](bf16x8 (&dst)[4][2], int bb, int mih){
    const unsigned short* p = Arow + bb * 16384 + mih * 1024;
#pragma unroll
    for (int mi=0;mi<4;++mi){
      dst[mi][0] = *(const bf16x8*)(p + mi * 1024 + ca0);
      dst[mi][1] = *(const bf16x8*)(p + mi * 1024 + ca1);
    }
  };
  auto rdB2 = [&](bf16x8 (&dst)[2][2], int bb, int nih){
    const unsigned short* p = Brow + bb * 16384 + nih * 1024;
#pragma unroll
    for (int ni=0;ni<2;++ni){
      dst[ni][0] = *(const bf16x8*)(p + ni * 1024 + ca0);
      dst[ni][1] = *(const bf16x8*)(p + ni * 1024 + ca1);
    }
  };

  // ---- 4-phase group: compute K-tile from buf bb, stage K-tile kn into bb.
  auto group = [&](int bb, int kn, bool st, bool last){
    bf16x8 aL[4][2], aH[4][2], b01[2][2], b23[2][2];
    // ph0: read A mi0-3 + B ni0-1 ; MFMA mi0-3 x ni0-1
    rdA4(aL, bb, 0); rdB2(b01, bb, 0);
    BAR(); LGKM0();
    __builtin_amdgcn_s_setprio(1);
#pragma unroll
    for (int mi=0;mi<4;++mi)
#pragma unroll
      for (int ni=0;ni<2;++ni){
        acc[mi][ni] = __builtin_amdgcn_mfma_f32_16x16x32_bf16(aL[mi][0], b01[ni][0], acc[mi][ni],0,0,0);
        acc[mi][ni] = __builtin_amdgcn_mfma_f32_16x16x32_bf16(aL[mi][1], b01[ni][1], acc[mi][ni],0,0,0);
      }
    __builtin_amdgcn_s_setprio(0);
    BAR();
    // ph1: read B ni2-3 ; MFMA mi0-3 x ni2-3
    rdB2(b23, bb, 2);
    BAR(); LGKM0();
    __builtin_amdgcn_s_setprio(1);
#pragma unroll
    for (int mi=0;mi<4;++mi)
#pragma unroll
      for (int ni=0;ni<2;++ni){
        acc[mi][2+ni] = __builtin_amdgcn_mfma_f32_16x16x32_bf16(aL[mi][0], b23[ni][0], acc[mi][2+ni],0,0,0);
        acc[mi][2+ni] = __builtin_amdgcn_mfma_f32_16x16x32_bf16(aL[mi][1], b23[ni][1], acc[mi][2+ni],0,0,0);
      }
    __builtin_amdgcn_s_setprio(0);
    BAR();
    // ph2: stage B(kn) (B tile fully read) ; read A mi4-7 ; MFMA mi4-7 x ni0-1
    if (st) stageB(bb, kn);
    rdA4(aH, bb, 4);
    BAR(); LGKM0();
    __builtin_amdgcn_s_setprio(1);
#pragma unroll
    for (int mi=0;mi<4;++mi)
#pragma unroll
      for (int ni=0;ni<2;++ni){
        acc[4+mi][ni] = __builtin_amdgcn_mfma_f32_16x16x32_bf16(aH[mi][0], b01[ni][0], acc[4+mi][ni],0,0,0);
        acc[4+mi][ni] = __builtin_amdgcn_mfma_f32_16x16x32_bf16(aH[mi][1], b01[ni][1], acc[4+mi][ni],0,0,0);
      }
    __builtin_amdgcn_s_setprio(0);
    BAR();
    // ph3: stage A(kn) (A tile fully read) ; MFMA mi4-7 x ni2-3 ; counted vmcnt
    if (st) stageA(bb, kn);
    BAR();
    __builtin_amdgcn_s_setprio(1);
#pragma unroll
    for (int mi=0;mi<4;++mi)
#pragma unroll
      for (int ni=0;ni<2;++ni){
        acc[4+mi][2+ni] = __builtin_amdgcn_mfma_f32_16x16x32_bf16(aH[mi][0], b23[ni][0], acc[4+mi][2+ni],0,0,0);
        acc[4+mi][2+ni] = __builtin_amdgcn_mfma_f32_16x16x32_bf16(aH[mi][1], b23[ni][1], acc[4+mi][2+ni],0,0,0);
      }
    __builtin_amdgcn_s_setprio(0);
    if (last) { VMC(0); } else { VMC(8); }   // force PREVIOUS K-tile landed
    BAR();
  };

  // ---- prologue: K-tiles 0 -> buf0, 1 -> buf1 (16 loads); force kt0 landed.
  stageB(0, 0); stageA(0, 0);
  stageB(1, 1); stageA(1, 1);
  VMC(8);
  BAR();

#pragma unroll 1
  for (int it = 0; it < 8; ++it){
    const bool st   = it < 7;
    const bool last = it == 7;
    group(0, 2*it + 2, st, last);
    group(1, 2*it + 3, st, last);
  }

  // ---- epilogue: C/D frag: col = lane&15 -> n, row = (lane>>4)*4 + reg -> m
  float bias[4];
#pragma unroll
  for (int ni=0;ni<4;++ni)
    bias[ni] = bsum[(size_t)t * C_N + n0 + wc*64 + ni*16 + lr];

#pragma unroll
  for (int mi=0;mi<8;++mi){
#pragma unroll
    for (int rr=0;rr<4;++rr){
      const int m = m0 + wr*128 + mi*16 + g*4 + rr;
      float* op = out + ((size_t)m * T_N + t) * C_N + n0 + wc*64 + lr;
#pragma unroll
      for (int ni=0;ni<4;++ni)
        op[ni*16] = acc[mi][ni][rr] + bias[ni];
    }
  }
}

extern "C" void kernel_launch(void* const* d_in, const int* in_sizes, int n_in,
                              void* d_out, int out_size, void* d_ws, size_t ws_size,
                              hipStream_t stream)
{
  const float* x   = (const float*)d_in[0];
  const float* Wsl = (const float*)d_in[1];
  const float* bsl = (const float*)d_in[2];
  const float* Wtr = (const float*)d_in[3];
  const float* btr = (const float*)d_in[4];
  float* out = (float*)d_out;

  const size_t WCAT_BYTES = (size_t)T_N * C_N * KTOT * 2;  // 17,825,792
  const size_t BS_BYTES   = (size_t)T_N * C_N * 4;         // 34,816
  char* ws = (char*)d_ws;
  unsigned short* wcat = (unsigned short*)ws;
  float*          bsum = (float*)(ws + WCAT_BYTES);
  unsigned short* acat = (unsigned short*)(ws + WCAT_BYTES + BS_BYTES);
  // total ws need = 160,466,944 B — identical to the previous (verified-fitting) layout

  prep_w  <<<dim3(2176), dim3(256), 0, stream>>>(Wsl, Wtr, wcat);
  prep_bsum<<<dim3(34),  dim3(256), 0, stream>>>(bsl, btr, bsum);
  prep_a  <<<dim3(1024), dim3(256), 0, stream>>>(x, acat);
  gemm8   <<<dim3(544),  dim3(512), 0, stream>>>(acat, wcat, bsum, out);
  (void)in_sizes; (void)n_in; (void)out_size; (void)ws_size;
}